// Round 6
// baseline (305.199 us; speedup 1.0000x reference)
//
#include <hip/hip_runtime.h>
#include <stdint.h>

#define K_SEL 512
#define NBOX 1536          // 3 * K_SEL
#define CAND_CAP 4096
#define HBITS 13
#define HBINS 8192         // 13-bit monotone-key histogram
#define NSHARD 128         // candidate-counter shards per scale
#define SEG 128            // entries per shard segment
#define HBLK 64            // hist blocks
#define HB0 8
#define HB1 16
#define HB2 40

// scale params
#define M0 32448           // 64*13*13*3
#define M1 129792          // 64*26*26*3
#define M2 519168          // 64*52*52*3
#define M_TOT (M0+M1+M2)   // 681408

// ws byte offsets
#define OFF_HIST 0u           // 64*8192*4 = 2097152
#define OFF_CNT  2097152u     // 3*128*4 = 1536 -> 2098688
#define OFF_THR  2098688u     // 32 -> 2098720
#define OFF_CAND 2098720u     // 3*128*128*8 = 393216 -> 2491936
#define OFF_BOX  2491936u     // 1536*7*4 = 43008 -> 2534944
#define OFF_SKEY 2534944u     // 1536*8 = 12288 -> 2547232

typedef unsigned long long u64;
typedef uint32_t u32;
typedef uint16_t u16;

__device__ __forceinline__ float sigf(float x) { return 1.0f / (1.0f + expf(-x)); }

__device__ __forceinline__ u32 fmono(float f) {
    u32 u = __float_as_uint(f);
    return (u & 0x80000000u) ? ~u : (u | 0x80000000u);
}

// ---------------- kernel 1: per-block LDS histogram -> private global slice ----------------
// Plane-order iteration (n,a,pix): conf reads fully coalesced (contiguous HW-planes).
// Each block writes its own slice (non-atomic); k_scan sums slices. Block 0 zeroes cnt.
__global__ __launch_bounds__(1024) void k_hist(const float* p0, const float* p1, const float* p2,
                                               uint8_t* ws) {
    __shared__ u32 lh[HBINS];
    for (int i = threadIdx.x; i < HBINS; i += 1024) lh[i] = 0;
    if (blockIdx.x == 0 && threadIdx.x < 3 * NSHARD) ((u32*)(ws + OFF_CNT))[threadIdx.x] = 0;
    __syncthreads();
    int b = blockIdx.x, s, b0, nb;
    if (b < HB0)            { s = 0; b0 = b;             nb = HB0; }
    else if (b < HB0 + HB1) { s = 1; b0 = b - HB0;       nb = HB1; }
    else                    { s = 2; b0 = b - HB0 - HB1; nb = HB2; }
    int M = (s == 0) ? M0 : (s == 1) ? M1 : M2;
    int H = (s == 0) ? 13 : (s == 1) ? 26 : 52;
    int HW = H * H;
    const float* p = (s == 0) ? p0 : (s == 1) ? p1 : p2;
    for (int o = b0 * 1024 + threadIdx.x; o < M; o += nb * 1024) {
        int n = o / (3 * HW); int rem = o - n * 3 * HW;
        int a = rem / HW;     int pix = rem - a * HW;
        float conf = sigf(p[(size_t)(n * 255 + a * 85) * HW + pix]);
        atomicAdd(&lh[fmono(conf) >> (32 - HBITS)], 1u);
    }
    __syncthreads();
    u32* slice = (u32*)(ws + OFF_HIST) + (u32)b * HBINS;
    for (int i = threadIdx.x; i < HBINS; i += 1024) slice[i] = lh[i];
}

// ---------------- kernel 2: sum slices + suffix scan -> threshold bin per scale ----------------
__global__ __launch_bounds__(1024) void k_scan(uint8_t* ws) {
    int s = blockIdx.x;
    int b0 = (s == 0) ? 0 : (s == 1) ? HB0 : (HB0 + HB1);
    int b1 = (s == 0) ? HB0 : (s == 1) ? (HB0 + HB1) : HBLK;
    __shared__ u32 sum[1024];
    int t = threadIdx.x;
    u32 bins[8];
#pragma unroll
    for (int k = 0; k < 8; ++k) bins[k] = 0;
    for (int b = b0; b < b1; ++b) {
        const uint4* sl = (const uint4*)((u32*)(ws + OFF_HIST) + (u32)b * HBINS + t * 8);
        uint4 x = sl[0], y = sl[1];
        bins[0] += x.x; bins[1] += x.y; bins[2] += x.z; bins[3] += x.w;
        bins[4] += y.x; bins[5] += y.y; bins[6] += y.z; bins[7] += y.w;
    }
    u32 acc = 0;
#pragma unroll
    for (int k = 0; k < 8; ++k) acc += bins[k];
    sum[t] = acc;
    __syncthreads();
    for (int off = 1; off < 1024; off <<= 1) {        // inclusive suffix scan
        u32 v = (t + off < 1024) ? sum[t + off] : 0;
        __syncthreads();
        sum[t] += v;
        __syncthreads();
    }
    u32 excl = (t < 1023) ? sum[t + 1] : 0;           // count in bins above my range
    u32 mine = sum[t] - excl;
    if (excl < K_SEL && excl + mine >= K_SEL) {
        u32 cum = excl; int thr = t * 8;
#pragma unroll
        for (int k = 7; k >= 0; --k) {
            cum += bins[k];
            if (cum >= K_SEL) { thr = t * 8 + k; break; }
        }
        ((u32*)(ws + OFF_THR))[s] = (u32)thr;
    }
}

// ---------------- kernel 3: compact candidates (plane-order coalesced, sharded counters) ----------------
__global__ __launch_bounds__(1024) void k_compact(const float* p0, const float* p1, const float* p2,
                                                  uint8_t* ws) {
    int t = blockIdx.x * 1024 + threadIdx.x;
    if (t >= M_TOT) return;
    int s, o, H;
    if (t < M0)            { s = 0; o = t;           H = 13; }
    else if (t < M0 + M1)  { s = 1; o = t - M0;      H = 26; }
    else                   { s = 2; o = t - M0 - M1; H = 52; }
    const float* p = (s == 0) ? p0 : (s == 1) ? p1 : p2;
    int HW = H * H;
    int n = o / (3 * HW); int rem = o - n * 3 * HW;
    int a = rem / HW;     int pix = rem - a * HW;
    float conf = sigf(p[(size_t)(n * 255 + a * 85) * HW + pix]);
    u32 cb = fmono(conf);
    if ((cb >> (32 - HBITS)) >= ((u32*)(ws + OFF_THR))[s]) {
        int c = n * (3 * HW) + pix * 3 + a;           // reference flat (n,h,w,a) index
        int idx = s * NSHARD + (blockIdx.x & (NSHARD - 1));
        u32 pos = atomicAdd(&((u32*)(ws + OFF_CNT))[idx], 1u);
        if (pos < SEG) {
            u64 key = ((u64)cb << 32) | (u32)(~(u32)c);   // ties: smaller c ranks higher
            ((u64*)(ws + OFF_CAND))[(u32)idx * SEG + pos] = key;
        }
    }
}

// ---------------- kernel 4: per-scale gather + bitonic sort + decode top-512 ----------------
__global__ __launch_bounds__(1024) void k_sortdec(const float* p0, const float* p1, const float* p2,
                                                  const float* a0, const float* a1, const float* a2,
                                                  uint8_t* ws) {
    int s = blockIdx.x;
    __shared__ u64 a_[CAND_CAP];           // 32 KB
    __shared__ u32 scnt[NSHARD], spre[NSHARD];
    __shared__ u32 total_s;
    __shared__ float pbv[512];
    __shared__ int pbi[512];
    int t = threadIdx.x;
    if (t < NSHARD) {
        u32 v = ((u32*)(ws + OFF_CNT))[s * NSHARD + t];
        scnt[t] = (v > SEG) ? SEG : v;
        spre[t] = scnt[t];
    }
    __syncthreads();
    for (int off = 1; off < NSHARD; off <<= 1) {       // inclusive Hillis-Steele
        u32 v = (t >= off && t < NSHARD) ? spre[t - off] : 0;
        __syncthreads();
        if (t < NSHARD) spre[t] += v;
        __syncthreads();
    }
    if (t == 0) total_s = (spre[NSHARD - 1] > CAND_CAP) ? CAND_CAP : spre[NSHARD - 1];
    __syncthreads();
    u32 total = total_s;
    int n2 = K_SEL;
    while (n2 < (int)total) n2 <<= 1;
    for (int i = t; i < n2; i += 1024) a_[i] = 0ull;
    __syncthreads();
    if (t < NSHARD) {                                   // thread t copies shard t
        u32 base = spre[t] - scnt[t];
        const u64* seg = (const u64*)(ws + OFF_CAND) + (u32)(s * NSHARD + t) * SEG;
        for (u32 i = 0; i < scnt[t]; ++i)
            if (base + i < CAND_CAP) a_[base + i] = seg[i];
    }
    __syncthreads();
    for (int k = 2; k <= n2; k <<= 1) {                 // bitonic, descending
        for (int j = k >> 1; j > 0; j >>= 1) {
            for (int i = t; i < n2; i += 1024) {
                int ixj = i ^ j;
                if (ixj > i) {
                    bool desc = ((i & k) == 0);
                    u64 x = a_[i], y = a_[ixj];
                    if (desc ? (x < y) : (x > y)) { a_[i] = y; a_[ixj] = x; }
                }
            }
            __syncthreads();
        }
    }
    // decode: box r handled by pair (r, r+512); partner scans classes [40,80)
    int H = (s == 0) ? 13 : (s == 1) ? 26 : 52;
    float stride = (s == 0) ? 32.f : (s == 1) ? 16.f : 8.f;
    const float* p    = (s == 0) ? p0 : (s == 1) ? p1 : p2;
    const float* anch = (s == 0) ? a0 : (s == 1) ? a1 : a2;
    int HW = H * H, hw3 = HW * 3;
    int r = t & 511;
    u64 key = a_[r];
    int c = (int)(~(u32)key);
    int n = c / hw3; int rem = c - n * hw3;
    int pix = rem / 3; int aa = rem - pix * 3;
    size_t base = (size_t)(n * 255 + aa * 85) * HW + pix;
    int k0 = (t < 512) ? 0 : 40;
    float best = -INFINITY; int bi = k0;
    for (int k2 = k0; k2 < k0 + 40; ++k2) {
        float vv = p[base + (size_t)(5 + k2) * HW];
        if (vv > best) { best = vv; bi = k2; }          // first-occurrence argmax
    }
    if (t >= 512) { pbv[r] = best; pbi[r] = bi; }
    __syncthreads();
    if (t < 512) {
        float v0 = p[base];
        float v1 = p[base + HW];
        float v2 = p[base + 2 * (size_t)HW];
        float v3 = p[base + 3 * (size_t)HW];
        float v4 = p[base + 4 * (size_t)HW];
        int h = pix / H, w = pix - h * H;
        float conf = sigf(v0);
        float cx = ((float)w + sigf(v1)) * stride;
        float cy = ((float)h + sigf(v2)) * stride;
        float bw = anch[aa * 2 + 0] * expf(v3);
        float bh = anch[aa * 2 + 1] * expf(v4);
        if (pbv[r] > best) { best = pbv[r]; bi = pbi[r]; }   // strict >: ties -> lower half
        int gi = s * K_SEL + r;
        float* box = (float*)(ws + OFF_BOX) + gi * 7;
        box[0] = (float)n; box[1] = conf; box[2] = cx; box[3] = cy;
        box[4] = bw; box[5] = bh; box[6] = (float)bi;
        u32 mono = (conf > 0.5f) ? fmono(conf) : fmono(-INFINITY);
        ((u64*)(ws + OFF_SKEY))[gi] = ((u64)mono << 32) | (u32)(~(u32)gi);  // ties: smaller pos first
    }
}

// ---------------- kernel 5: sort 1536 + bucket-chain NMS + output (single block) ----------------
__global__ __launch_bounds__(1024) void k_tail(uint8_t* ws, float* out) {
    __shared__ u64 a_[2048];                                        // 16384 B
    __shared__ float gx1[NBOX], gy1[NBOX], gx2[NBOX], gy2[NBOX], gar[NBOX];  // 30720 B
    __shared__ u16 perm[NBOX], lbk[NBOX], nxt[NBOX];                // 9216 B
    __shared__ uint8_t keepf[NBOX], valf[NBOX], ishead[NBOX];       // 4608 B
    int t = threadIdx.x;
    u64* skey = (u64*)(ws + OFF_SKEY);
    for (int i = t; i < 2048; i += 1024) a_[i] = (i < NBOX) ? skey[i] : 0ull;
    __syncthreads();
    for (int k = 2; k <= 2048; k <<= 1) {               // bitonic, descending (stable via key)
        for (int j = k >> 1; j > 0; j >>= 1) {
            for (int i = t; i < 2048; i += 1024) {
                int ixj = i ^ j;
                if (ixj > i) {
                    bool desc = ((i & k) == 0);
                    u64 x = a_[i], y = a_[ixj];
                    if (desc ? (x < y) : (x > y)) { a_[i] = y; a_[ixj] = x; }
                }
            }
            __syncthreads();
        }
    }
    const float* box = (const float*)(ws + OFF_BOX);
    for (int i = t; i < NBOX; i += 1024) {
        int pos = (int)(~(u32)a_[i]);
        perm[i] = (u16)pos;
        float b0 = box[pos * 7 + 0], b1 = box[pos * 7 + 1], b2 = box[pos * 7 + 2];
        float b3 = box[pos * 7 + 3], b4 = box[pos * 7 + 4], b5 = box[pos * 7 + 5];
        float b6 = box[pos * 7 + 6];
        gx1[i] = b2 - b4 * 0.5f;  gy1[i] = b3 - b5 * 0.5f;
        gx2[i] = b2 + b4 * 0.5f;  gy2[i] = b3 + b5 * 0.5f;
        gar[i] = b4 * b5;
        lbk[i] = (u16)((int)b0 * 80 + (int)b6);         // (image, class) bucket, exact small ints
        valf[i] = (b1 > 0.5f) ? 1 : 0;
        keepf[i] = 0; nxt[i] = 0xFFFF; ishead[i] = 0;
    }
    __syncthreads();
    // prev[i] = largest j<i in same bucket -> next links (unique writes); heads have none
    for (int i = t; i < NBOX; i += 1024) {
        u16 b = lbk[i]; int prev = -1;
        for (int j = i - 1; j >= 0; --j)
            if (lbk[j] == b) { prev = j; break; }
        if (prev >= 0) nxt[prev] = (u16)i; else ishead[i] = 1;
    }
    __syncthreads();
    // per-head serial greedy over its chain (buckets are tiny; all LDS)
    for (int i = t; i < NBOX; i += 1024) {
        if (!ishead[i]) continue;
        for (int v = i; v != 0xFFFF; v = nxt[v]) {
            bool sup = false;
            for (int u = i; u != v; u = nxt[u]) {
                if (!keepf[u]) continue;                 // only active boxes suppress
                float ix1 = fmaxf(gx1[u], gx1[v]), iy1 = fmaxf(gy1[u], gy1[v]);
                float ix2 = fminf(gx2[u], gx2[v]), iy2 = fminf(gy2[u], gy2[v]);
                float iw = fmaxf(ix2 - ix1, 0.f), ih = fmaxf(iy2 - iy1, 0.f);
                float inter = iw * ih;
                float iou = inter / (gar[u] + gar[v] - inter + 1e-9f);
                if (iou > 0.1f) { sup = true; break; }
            }
            keepf[v] = (valf[v] && !sup) ? 1 : 0;
        }
    }
    __syncthreads();
    for (int i = t; i < NBOX; i += 1024) {
        float kf = keepf[i] ? 1.f : 0.f;
        int pos = perm[i];
        for (int k = 0; k < 7; ++k) out[i * 7 + k] = box[pos * 7 + k] * kf;
        out[NBOX * 7 + i] = kf;
    }
}

extern "C" void kernel_launch(void* const* d_in, const int* in_sizes, int n_in,
                              void* d_out, int out_size, void* d_ws, size_t ws_size,
                              hipStream_t stream) {
    const float* p0 = (const float*)d_in[0];
    const float* p1 = (const float*)d_in[1];
    const float* p2 = (const float*)d_in[2];
    const float* a0 = (const float*)d_in[3];
    const float* a1 = (const float*)d_in[4];
    const float* a2 = (const float*)d_in[5];
    uint8_t* ws = (uint8_t*)d_ws;
    float* out = (float*)d_out;

    const int CB = (M_TOT + 1023) / 1024;  // 666

    k_hist   <<<HBLK, 1024, 0, stream>>>(p0, p1, p2, ws);
    k_scan   <<<3, 1024, 0, stream>>>(ws);
    k_compact<<<CB, 1024, 0, stream>>>(p0, p1, p2, ws);
    k_sortdec<<<3, 1024, 0, stream>>>(p0, p1, p2, a0, a1, a2, ws);
    k_tail   <<<1, 1024, 0, stream>>>(ws, out);
}